// Round 1
// baseline (173.151 us; speedup 1.0000x reference)
//
#include <hip/hip_runtime.h>
#include <math.h>

#define GSZ   16
#define NPIX  256
#define NCLS  4
#define NCTL  4
#define HID   64
#define LBIG  1.0e6f
#define KMAX  256
#define PW    18            // padded width for g
#define PPIX  (PW*PW)       // 324

__global__ __launch_bounds__(256, 2) void semirl_kernel(
    const float* __restrict__ grid_cnt,  // (B,4,16,16)
    const int*   __restrict__ loc,       // (B,2)
    const int*   __restrict__ goal,      // (B,2)
    const float* __restrict__ theta,     // (4,16,16)
    const float* __restrict__ w1,        // (64,4,3,3)
    const float* __restrict__ b1,        // (64)
    const float* __restrict__ w2,        // (4,64,3,3)
    const float* __restrict__ b2,        // (4)
    float*       __restrict__ out,       // logits (B,4) then probs (B,4)
    int B)
{
    const int b   = blockIdx.x;
    const int tid = threadIdx.x;
    const int r   = tid >> 4;
    const int c   = tid & 15;

    __shared__ float  s_sem[NCLS][NPIX];     // 4 KB
    __shared__ float4 s_h4[HID/4][NPIX];     // 64 KB
    __shared__ float  s_cost[NCTL][NPIX];    // 4 KB
    __shared__ float  s_g[2][PPIX];          // 2.6 KB
    __shared__ int    s_any2[2];

    // ---------------- phase 0: per-pixel class softmax ----------------
    const float* gb = grid_cnt + (size_t)b * (NCLS * NPIX);
    {
        float x0 = gb[0*NPIX + tid] * theta[0*NPIX + tid];
        float x1 = gb[1*NPIX + tid] * theta[1*NPIX + tid];
        float x2 = gb[2*NPIX + tid] * theta[2*NPIX + tid];
        float x3 = gb[3*NPIX + tid] * theta[3*NPIX + tid];
        float m  = fmaxf(fmaxf(x0, x1), fmaxf(x2, x3));
        float e0 = expf(x0 - m), e1 = expf(x1 - m), e2 = expf(x2 - m), e3 = expf(x3 - m);
        float inv = 1.0f / (e0 + e1 + e2 + e3);
        s_sem[0][tid] = e0 * inv;
        s_sem[1][tid] = e1 * inv;
        s_sem[2][tid] = e2 * inv;
        s_sem[3][tid] = e3 * inv;
    }
    // fill both g buffers (incl. border ring) with L
    for (int i = tid; i < 2 * PPIX; i += 256) ((float*)s_g)[i] = LBIG;
    if (tid == 0) { s_any2[0] = 0; s_any2[1] = 0; }
    __syncthreads();

    // ---------------- phase 1: conv 4->64, ReLU ----------------
    float acc[HID];
    #pragma unroll
    for (int o = 0; o < HID; ++o) acc[o] = b1[o];

    #pragma unroll
    for (int kr = 0; kr < 3; ++kr) {
        const int rr = r + kr - 1;
        #pragma unroll
        for (int kc = 0; kc < 3; ++kc) {
            const int cc2 = c + kc - 1;
            if (rr >= 0 && rr < GSZ && cc2 >= 0 && cc2 < GSZ) {
                const int np = rr * GSZ + cc2;
                #pragma unroll
                for (int ci = 0; ci < NCLS; ++ci) {
                    const float s = s_sem[ci][np];
                    const float* wp = w1 + ci * 9 + kr * 3 + kc;
                    #pragma unroll
                    for (int o = 0; o < HID; ++o)
                        acc[o] = fmaf(s, wp[o * 36], acc[o]);
                }
            }
        }
    }
    // ReLU + store h as float4 channel-groups
    #pragma unroll
    for (int g4 = 0; g4 < HID / 4; ++g4) {
        float4 v;
        v.x = fmaxf(acc[4*g4 + 0], 0.0f);
        v.y = fmaxf(acc[4*g4 + 1], 0.0f);
        v.z = fmaxf(acc[4*g4 + 2], 0.0f);
        v.w = fmaxf(acc[4*g4 + 3], 0.0f);
        s_h4[g4][tid] = v;
    }
    __syncthreads();

    // ---------------- phase 2: conv 64->4, softplus ----------------
    float cst[NCTL] = { b2[0], b2[1], b2[2], b2[3] };
    #pragma unroll
    for (int kr = 0; kr < 3; ++kr) {
        const int rr = r + kr - 1;
        #pragma unroll
        for (int kc = 0; kc < 3; ++kc) {
            const int cc2 = c + kc - 1;
            if (rr >= 0 && rr < GSZ && cc2 >= 0 && cc2 < GSZ) {
                const int np  = rr * GSZ + cc2;
                const int tap = kr * 3 + kc;
                #pragma unroll
                for (int g4 = 0; g4 < HID / 4; ++g4) {
                    const float4 hv = s_h4[g4][np];
                    #pragma unroll
                    for (int u = 0; u < NCTL; ++u) {
                        const float* wp = w2 + u * (HID * 9) + (4 * g4) * 9 + tap;
                        cst[u] += hv.x * wp[0] + hv.y * wp[9] + hv.z * wp[18] + hv.w * wp[27];
                    }
                }
            }
        }
    }
    #pragma unroll
    for (int u = 0; u < NCTL; ++u) {
        float x = cst[u];
        // softplus = logaddexp(x,0) = max(x,0) + log1p(exp(-|x|)); +1e-6
        cst[u] = fmaxf(x, 0.0f) + log1pf(expf(-fabsf(x))) + 1e-6f;
        s_cost[u][tid] = cst[u];
    }

    // ---------------- phase 3: value iteration ----------------
    const int gr = goal[2*b], gc = goal[2*b + 1];
    const int goalt = gr * GSZ + gc;
    const int pp = (r + 1) * PW + (c + 1);
    float greg = (tid == goalt) ? 0.0f : LBIG;
    if (tid == goalt) s_g[0][pp] = 0.0f;
    __syncthreads();   // covers s_cost, goal write

    int cur = 0;
    for (int k = 1; k <= KMAX; ++k) {
        const float* gcur = s_g[cur];
        const float up = gcur[pp - PW];
        const float dn = gcur[pp + PW];
        const float lf = gcur[pp - 1];
        const float rt = gcur[pp + 1];
        // MOVES order: (-1,0),(1,0),(0,-1),(0,1)
        float q  = fminf(fminf(cst[0] + up, cst[1] + dn),
                         fminf(cst[2] + lf, cst[3] + rt));
        float ng = fminf(greg, q);
        const int changed = (ng < greg);
        s_g[cur ^ 1][pp] = ng;
        greg = ng;
        cur ^= 1;
        if (changed) s_any2[k & 1] = k;   // benign same-value race
        __syncthreads();
        if (s_any2[k & 1] != k) break;    // no change in this sweep -> fixed point
    }

    // ---------------- phase 4: Q gather + output softmax ----------------
    if (tid == 0) {
        const int lr = loc[2*b], lc = loc[2*b + 1];
        const int lp  = lr * GSZ + lc;
        const int lpp = (lr + 1) * PW + (lc + 1);
        const float* gf = s_g[cur];
        float Q0 = s_cost[0][lp] + gf[lpp - PW];
        float Q1 = s_cost[1][lp] + gf[lpp + PW];
        float Q2 = s_cost[2][lp] + gf[lpp - 1];
        float Q3 = s_cost[3][lp] + gf[lpp + 1];
        float l0 = -Q0, l1 = -Q1, l2 = -Q2, l3 = -Q3;
        float m  = fmaxf(fmaxf(l0, l1), fmaxf(l2, l3));
        float e0 = expf(l0 - m), e1 = expf(l1 - m), e2 = expf(l2 - m), e3 = expf(l3 - m);
        float inv = 1.0f / (e0 + e1 + e2 + e3);
        float* lo = out + (size_t)b * 4;
        float* po = out + (size_t)B * 4 + (size_t)b * 4;
        lo[0] = l0; lo[1] = l1; lo[2] = l2; lo[3] = l3;
        po[0] = e0 * inv; po[1] = e1 * inv; po[2] = e2 * inv; po[3] = e3 * inv;
    }
}

extern "C" void kernel_launch(void* const* d_in, const int* in_sizes, int n_in,
                              void* d_out, int out_size, void* d_ws, size_t ws_size,
                              hipStream_t stream) {
    const float* grid_cnt = (const float*)d_in[0];
    const int*   loc      = (const int*)  d_in[1];
    const int*   goal     = (const int*)  d_in[2];
    const float* theta    = (const float*)d_in[3];
    const float* w1       = (const float*)d_in[4];
    const float* b1       = (const float*)d_in[5];
    const float* w2       = (const float*)d_in[6];
    const float* b2       = (const float*)d_in[7];
    float*       outp     = (float*)d_out;
    const int B = in_sizes[1] / 2;   // loc_batch is (B,2)

    hipLaunchKernelGGL(semirl_kernel, dim3(B), dim3(256), 0, stream,
                       grid_cnt, loc, goal, theta, w1, b1, w2, b2, outp, B);
}

// Round 4
// 102.093 us; speedup vs baseline: 1.6960x; 1.6960x over previous
//
#include <hip/hip_runtime.h>
#include <math.h>

#define GSZ   16
#define NPIX  256
#define NCTL  4
#define LBIG  1.0e6f
#define KMAX  256
#define PW    18
#define PP18  324

typedef __fp16 h2v __attribute__((ext_vector_type(2)));
union UH2 { unsigned u; h2v h; };

__device__ __forceinline__ float dot2f(unsigned a, unsigned b, float acc) {
    UH2 x; x.u = a; UH2 y; y.u = b;
    return __builtin_amdgcn_fdot2(x.h, y.h, acc, false);
}

__device__ __forceinline__ unsigned pk2(float a, float b) {
    UH2 u; u.h = __builtin_amdgcn_cvt_pkrtz(a, b);
    return u.u;
}

__global__ __launch_bounds__(256, 4) void semirl_kernel(
    const float* __restrict__ grid_cnt,  // (B,4,16,16)
    const int*   __restrict__ loc,       // (B,2)
    const int*   __restrict__ goal,      // (B,2)
    const float* __restrict__ theta,     // (4,16,16)
    const float* __restrict__ w1,        // (64,4,3,3)
    const float* __restrict__ b1,        // (64)
    const float* __restrict__ w2,        // (4,64,3,3)
    const float* __restrict__ b2,        // (4)
    float*       __restrict__ out,       // logits (B,4) then probs (B,4)
    int B)
{
    const int b   = blockIdx.x;
    const int tid = threadIdx.x;
    const int r   = tid >> 4;
    const int c   = tid & 15;
    const int pp  = (r + 1) * PW + (c + 1);

    __shared__ unsigned s_sem2[2][PP18];   // fp16x2 class pairs, zero-padded ring
    __shared__ unsigned s_h2[16][PP18];    // fp16x2 channel pairs (one 32-ch chunk)
    __shared__ float    s_cost[NCTL][NPIX];
    __shared__ float    s_gout[NPIX];
    __shared__ unsigned s_pw1[1152];       // [tap][pair2][out64] packed fp16x2
    __shared__ unsigned s_pw2[1152];       // [tap][pair32][u4]   packed fp16x2

    // ---- phase 0: zero pads, pack weights, per-pixel class softmax ----
    {
        unsigned* z = &s_sem2[0][0];
        for (int i = tid; i < 2 * PP18; i += 256) z[i] = 0;
        unsigned* z2 = &s_h2[0][0];
        for (int i = tid; i < 16 * PP18; i += 256) z2[i] = 0;
    }
    for (int i = tid; i < 1152; i += 256) {       // pw1[(tap*2+p)*64+o]
        int o = i & 63, p = (i >> 6) & 1, tap = i >> 7;
        s_pw1[i] = pk2(w1[(o * 4 + 2 * p) * 9 + tap],
                       w1[(o * 4 + 2 * p + 1) * 9 + tap]);
    }
    for (int i = tid; i < 1152; i += 256) {       // pw2[(tap*32+p)*4+u]
        int u = i & 3, p = (i >> 2) & 31, tap = i >> 7;
        s_pw2[i] = pk2(w2[(u * 64 + 2 * p) * 9 + tap],
                       w2[(u * 64 + 2 * p + 1) * 9 + tap]);
    }
    unsigned semA, semB;
    {
        const float* gb = grid_cnt + (size_t)b * (4 * NPIX);
        float x0 = gb[0 * NPIX + tid] * theta[0 * NPIX + tid];
        float x1 = gb[1 * NPIX + tid] * theta[1 * NPIX + tid];
        float x2 = gb[2 * NPIX + tid] * theta[2 * NPIX + tid];
        float x3 = gb[3 * NPIX + tid] * theta[3 * NPIX + tid];
        float m  = fmaxf(fmaxf(x0, x1), fmaxf(x2, x3));
        float e0 = expf(x0 - m), e1 = expf(x1 - m), e2 = expf(x2 - m), e3 = expf(x3 - m);
        float inv = 1.0f / (e0 + e1 + e2 + e3);
        semA = pk2(e0 * inv, e1 * inv);
        semB = pk2(e2 * inv, e3 * inv);
    }
    __syncthreads();               // zero-fill complete
    s_sem2[0][pp] = semA;
    s_sem2[1][pp] = semB;
    __syncthreads();               // sem + packed weights ready

    // ---- conv1 (4->64, fp16 dot2, 32-ch chunks) + conv2 (64->4) ----
    float cst[NCTL] = { b2[0], b2[1], b2[2], b2[3] };

    #pragma unroll
    for (int ch2 = 0; ch2 < 2; ++ch2) {
        float acc[32];
        #pragma unroll
        for (int o = 0; o < 32; ++o) acc[o] = b1[ch2 * 32 + o];

        #pragma unroll
        for (int tap = 0; tap < 9; ++tap) {
            const int off = (tap / 3 - 1) * PW + (tap % 3 - 1);
            #pragma unroll
            for (int p = 0; p < 2; ++p) {
                const unsigned hv = s_sem2[p][pp + off];
                const unsigned* wb = &s_pw1[(tap * 2 + p) * 64 + ch2 * 32];
                #pragma unroll
                for (int o = 0; o < 32; ++o)
                    acc[o] = dot2f(hv, wb[o], acc[o]);
            }
        }
        // relu + pack to fp16 pairs
        #pragma unroll
        for (int o2 = 0; o2 < 16; ++o2)
            s_h2[o2][pp] = pk2(fmaxf(acc[2 * o2], 0.0f), fmaxf(acc[2 * o2 + 1], 0.0f));
        __syncthreads();           // h chunk ready

        #pragma unroll
        for (int tap = 0; tap < 9; ++tap) {
            const int off = (tap / 3 - 1) * PW + (tap % 3 - 1);
            #pragma unroll
            for (int p = 0; p < 16; ++p) {
                const unsigned hv = s_h2[p][pp + off];
                const unsigned* wb = &s_pw2[(tap * 32 + ch2 * 16 + p) * 4];
                #pragma unroll
                for (int u = 0; u < NCTL; ++u)
                    cst[u] = dot2f(hv, wb[u], cst[u]);
            }
        }
        __syncthreads();           // conv2 done reading before next chunk overwrite
    }

    // softplus -> cost
    #pragma unroll
    for (int u = 0; u < NCTL; ++u) {
        float x = cst[u];
        s_cost[u][tid] = fmaxf(x, 0.0f) + log1pf(expf(-fabsf(x))) + 1e-6f;
    }
    __syncthreads();               // cost visible to all waves

    // ---- value iteration: register-resident, shuffle-based, per-wave ----
    const int lane = tid & 63;
    const int cv   = lane & 15;          // column
    const int rgv  = lane >> 4;          // row group (4 rows each)
    const int r0   = rgv * 4;

    float cs[4][NCTL];
    #pragma unroll
    for (int i = 0; i < 4; ++i)
        #pragma unroll
        for (int u = 0; u < NCTL; ++u)
            cs[i][u] = s_cost[u][(r0 + i) * GSZ + cv];

    const int grr = goal[2 * b], gcc = goal[2 * b + 1];
    float g[4];
    #pragma unroll
    for (int i = 0; i < 4; ++i)
        g[i] = (cv == gcc && (r0 + i) == grr) ? 0.0f : LBIG;

    for (int k = 0; k < KMAX; ++k) {
        float gu = __shfl_up(g[3], 16);
        float gd = __shfl_down(g[0], 16);
        float lf[4], rt[4];
        #pragma unroll
        for (int i = 0; i < 4; ++i) { lf[i] = __shfl_up(g[i], 1); rt[i] = __shfl_down(g[i], 1); }
        const float up0 = (rgv > 0) ? gu : LBIG;
        const float dn3 = (rgv < 3) ? gd : LBIG;
        #pragma unroll
        for (int i = 0; i < 4; ++i) {
            lf[i] = (cv > 0)  ? lf[i] : LBIG;
            rt[i] = (cv < 15) ? rt[i] : LBIG;
        }
        const float up[4] = { up0, g[0], g[1], g[2] };
        const float dn[4] = { g[1], g[2], g[3], dn3 };
        float ng[4];
        bool ch = false;
        #pragma unroll
        for (int i = 0; i < 4; ++i) {
            float q = fminf(fminf(cs[i][0] + up[i], cs[i][1] + dn[i]),
                            fminf(cs[i][2] + lf[i], cs[i][3] + rt[i]));
            ng[i] = fminf(g[i], q);
            ch = ch || (ng[i] < g[i]);
        }
        #pragma unroll
        for (int i = 0; i < 4; ++i) g[i] = ng[i];
        if (__ballot(ch) == 0ULL) break;   // fixed point (identical across waves)
    }

    #pragma unroll
    for (int i = 0; i < 4; ++i)
        s_gout[(r0 + i) * GSZ + cv] = g[i];   // all waves write identical values
    __syncthreads();

    // ---- Q gather + output softmax ----
    if (tid == 0) {
        const int lr = loc[2 * b], lc = loc[2 * b + 1];
        const int lp = lr * GSZ + lc;
        float Q0 = s_cost[0][lp] + s_gout[lp - GSZ];
        float Q1 = s_cost[1][lp] + s_gout[lp + GSZ];
        float Q2 = s_cost[2][lp] + s_gout[lp - 1];
        float Q3 = s_cost[3][lp] + s_gout[lp + 1];
        float l0 = -Q0, l1 = -Q1, l2 = -Q2, l3 = -Q3;
        float m  = fmaxf(fmaxf(l0, l1), fmaxf(l2, l3));
        float e0 = expf(l0 - m), e1 = expf(l1 - m), e2 = expf(l2 - m), e3 = expf(l3 - m);
        float inv = 1.0f / (e0 + e1 + e2 + e3);
        float* lo = out + (size_t)b * 4;
        float* po = out + (size_t)B * 4 + (size_t)b * 4;
        lo[0] = l0; lo[1] = l1; lo[2] = l2; lo[3] = l3;
        po[0] = e0 * inv; po[1] = e1 * inv; po[2] = e2 * inv; po[3] = e3 * inv;
    }
}

extern "C" void kernel_launch(void* const* d_in, const int* in_sizes, int n_in,
                              void* d_out, int out_size, void* d_ws, size_t ws_size,
                              hipStream_t stream) {
    const float* grid_cnt = (const float*)d_in[0];
    const int*   loc      = (const int*)  d_in[1];
    const int*   goal     = (const int*)  d_in[2];
    const float* theta    = (const float*)d_in[3];
    const float* w1       = (const float*)d_in[4];
    const float* b1       = (const float*)d_in[5];
    const float* w2       = (const float*)d_in[6];
    const float* b2       = (const float*)d_in[7];
    float*       outp     = (float*)d_out;
    const int B = in_sizes[1] / 2;   // loc_batch is (B,2)

    hipLaunchKernelGGL(semirl_kernel, dim3(B), dim3(256), 0, stream,
                       grid_cnt, loc, goal, theta, w1, b1, w2, b2, outp, B);
}

// Round 5
// 91.224 us; speedup vs baseline: 1.8981x; 1.1191x over previous
//
#include <hip/hip_runtime.h>
#include <math.h>

#define GSZ   16
#define NPIX  256
#define NCTL  4
#define LBIG  1.0e6f
#define KMAX  256
#define PW    18
#define PP18  324
#define HSTR  20          // u32 words per pixel in h tile (16 pairs + 4 pad, 16B aligned)

typedef __fp16 h2v __attribute__((ext_vector_type(2)));
union UH2 { unsigned u; h2v h; };
union UF  { unsigned u; float f; };

__device__ __forceinline__ float dot2f(unsigned a, unsigned b, float acc) {
    UH2 x; x.u = a; UH2 y; y.u = b;
    return __builtin_amdgcn_fdot2(x.h, y.h, acc, false);
}
__device__ __forceinline__ unsigned pk2(float a, float b) {
    UH2 u; u.h = __builtin_amdgcn_cvt_pkrtz(a, b);
    return u.u;
}
// value from lane-1 within each 16-lane row: DPP row_shr:1 (0x111)
__device__ __forceinline__ float dpp_up1(float x) {
    UF s; s.f = x;
    UF r; r.u = __builtin_amdgcn_update_dpp(0, (int)s.u, 0x111, 0xF, 0xF, true);
    return r.f;
}
// value from lane+1 within each 16-lane row: DPP row_shl:1 (0x101)
__device__ __forceinline__ float dpp_dn1(float x) {
    UF s; s.f = x;
    UF r; r.u = __builtin_amdgcn_update_dpp(0, (int)s.u, 0x101, 0xF, 0xF, true);
    return r.f;
}

// ---- prep: pack fp16x2 weights into d_ws (loop-linear, s_load-friendly) ----
// pw1[ ch2*576 + tap*64 + p*32 + o ]  = pk2(w1[o_glob][2p][tap], w1[o_glob][2p+1][tap])
// pw2[ ch2*576 + tap*64 + p*4  + u ]  = pk2(w2[u][cin=ch2*32+2p][tap], w2[u][cin+1][tap])
__global__ void pack_weights(const float* __restrict__ w1,
                             const float* __restrict__ w2,
                             unsigned*    __restrict__ pw) {
    int i = blockIdx.x * 256 + threadIdx.x;
    if (i < 1152) {
        int o   = i & 31;
        int p   = (i >> 5) & 1;
        int tap = (i >> 6) % 9;
        int ch2 = (i >> 6) / 9;
        int og  = ch2 * 32 + o;
        pw[i] = pk2(w1[og * 36 + (2 * p) * 9 + tap],
                    w1[og * 36 + (2 * p + 1) * 9 + tap]);
    } else if (i < 2304) {
        int j   = i - 1152;
        int u   = j & 3;
        int p   = (j >> 2) & 15;
        int tap = (j >> 6) % 9;
        int ch2 = (j >> 6) / 9;
        int cin = ch2 * 32 + 2 * p;
        pw[i] = pk2(w2[(u * 64 + cin) * 9 + tap],
                    w2[(u * 64 + cin + 1) * 9 + tap]);
    }
}

__global__ __launch_bounds__(256, 4) void semirl_kernel(
    const float*    __restrict__ grid_cnt,  // (B,4,16,16)
    const int*      __restrict__ loc,       // (B,2)
    const int*      __restrict__ goal,      // (B,2)
    const float*    __restrict__ theta,     // (4,16,16)
    const float*    __restrict__ b1,        // (64)
    const float*    __restrict__ b2,        // (4)
    const unsigned* __restrict__ pw,        // packed weights in d_ws
    float*          __restrict__ out,       // logits (B,4) then probs (B,4)
    int B)
{
    const int b   = blockIdx.x;
    const int tid = threadIdx.x;
    const int r   = tid >> 4;
    const int c   = tid & 15;
    const int pp  = (r + 1) * PW + (c + 1);

    __shared__ unsigned s_sem[PP18 * 2];     // fp16x2 class pairs [pix][2], zero ring
    __shared__ unsigned s_h[PP18 * HSTR];    // fp16x2 ch pairs [pix][20], zero ring
    __shared__ float    s_cost[NCTL][NPIX];
    __shared__ float    s_gout[NPIX];

    const unsigned* pw1g = pw;
    const unsigned* pw2g = pw + 1152;

    // ---- phase 0: zero rings, per-pixel class softmax ----
    for (int i = tid; i < PP18 * 2; i += 256) s_sem[i] = 0;
    for (int i = tid; i < PP18 * HSTR; i += 256) s_h[i] = 0;

    unsigned semA, semB;
    {
        const float* gb = grid_cnt + (size_t)b * (4 * NPIX);
        float x0 = gb[0 * NPIX + tid] * theta[0 * NPIX + tid];
        float x1 = gb[1 * NPIX + tid] * theta[1 * NPIX + tid];
        float x2 = gb[2 * NPIX + tid] * theta[2 * NPIX + tid];
        float x3 = gb[3 * NPIX + tid] * theta[3 * NPIX + tid];
        float m  = fmaxf(fmaxf(x0, x1), fmaxf(x2, x3));
        float e0 = expf(x0 - m), e1 = expf(x1 - m), e2 = expf(x2 - m), e3 = expf(x3 - m);
        float inv = 1.0f / (e0 + e1 + e2 + e3);
        semA = pk2(e0 * inv, e1 * inv);
        semB = pk2(e2 * inv, e3 * inv);
    }
    __syncthreads();               // zero-fill complete
    s_sem[pp * 2 + 0] = semA;
    s_sem[pp * 2 + 1] = semB;
    __syncthreads();               // sem ready

    // ---- conv1 (4->64, fp16 dot2, SGPR weights) + conv2 (64->4) ----
    float cst[NCTL] = { b2[0], b2[1], b2[2], b2[3] };

    #pragma unroll
    for (int ch2 = 0; ch2 < 2; ++ch2) {
        float acc[32];
        #pragma unroll
        for (int o = 0; o < 32; ++o) acc[o] = b1[ch2 * 32 + o];

        #pragma unroll
        for (int tap = 0; tap < 9; ++tap) {
            const int off = (tap / 3 - 1) * PW + (tap % 3 - 1);
            const uint2 sv = *(const uint2*)&s_sem[(pp + off) * 2];
            const uint4* wq0 = (const uint4*)&pw1g[(ch2 * 9 + tap) * 64];
            const uint4* wq1 = (const uint4*)&pw1g[(ch2 * 9 + tap) * 64 + 32];
            #pragma unroll
            for (int j = 0; j < 8; ++j) {        // p = 0 (classes 0,1)
                const uint4 w = wq0[j];
                acc[4*j+0] = dot2f(sv.x, w.x, acc[4*j+0]);
                acc[4*j+1] = dot2f(sv.x, w.y, acc[4*j+1]);
                acc[4*j+2] = dot2f(sv.x, w.z, acc[4*j+2]);
                acc[4*j+3] = dot2f(sv.x, w.w, acc[4*j+3]);
            }
            #pragma unroll
            for (int j = 0; j < 8; ++j) {        // p = 1 (classes 2,3)
                const uint4 w = wq1[j];
                acc[4*j+0] = dot2f(sv.y, w.x, acc[4*j+0]);
                acc[4*j+1] = dot2f(sv.y, w.y, acc[4*j+1]);
                acc[4*j+2] = dot2f(sv.y, w.z, acc[4*j+2]);
                acc[4*j+3] = dot2f(sv.y, w.w, acc[4*j+3]);
            }
        }
        // relu + pack h pairs, b128 stores
        #pragma unroll
        for (int j = 0; j < 4; ++j) {
            uint4 v;
            v.x = pk2(fmaxf(acc[8*j+0], 0.0f), fmaxf(acc[8*j+1], 0.0f));
            v.y = pk2(fmaxf(acc[8*j+2], 0.0f), fmaxf(acc[8*j+3], 0.0f));
            v.z = pk2(fmaxf(acc[8*j+4], 0.0f), fmaxf(acc[8*j+5], 0.0f));
            v.w = pk2(fmaxf(acc[8*j+6], 0.0f), fmaxf(acc[8*j+7], 0.0f));
            *(uint4*)&s_h[pp * HSTR + 4*j] = v;
        }
        __syncthreads();           // h chunk ready

        #pragma unroll
        for (int tap = 0; tap < 9; ++tap) {
            const int off = (tap / 3 - 1) * PW + (tap % 3 - 1);
            const unsigned* hb = &s_h[(pp + off) * HSTR];
            const uint4* wq = (const uint4*)&pw2g[(ch2 * 9 + tap) * 64];
            #pragma unroll
            for (int j = 0; j < 4; ++j) {        // p = 4j..4j+3
                const uint4 hv = *(const uint4*)&hb[4*j];
                const uint4 wA = wq[4*j+0], wB = wq[4*j+1], wC = wq[4*j+2], wD = wq[4*j+3];
                cst[0] = dot2f(hv.x, wA.x, cst[0]); cst[1] = dot2f(hv.x, wA.y, cst[1]);
                cst[2] = dot2f(hv.x, wA.z, cst[2]); cst[3] = dot2f(hv.x, wA.w, cst[3]);
                cst[0] = dot2f(hv.y, wB.x, cst[0]); cst[1] = dot2f(hv.y, wB.y, cst[1]);
                cst[2] = dot2f(hv.y, wB.z, cst[2]); cst[3] = dot2f(hv.y, wB.w, cst[3]);
                cst[0] = dot2f(hv.z, wC.x, cst[0]); cst[1] = dot2f(hv.z, wC.y, cst[1]);
                cst[2] = dot2f(hv.z, wC.z, cst[2]); cst[3] = dot2f(hv.z, wC.w, cst[3]);
                cst[0] = dot2f(hv.w, wD.x, cst[0]); cst[1] = dot2f(hv.w, wD.y, cst[1]);
                cst[2] = dot2f(hv.w, wD.z, cst[2]); cst[3] = dot2f(hv.w, wD.w, cst[3]);
            }
        }
        __syncthreads();           // conv2 done before chunk1 overwrites h
    }

    // softplus -> cost
    #pragma unroll
    for (int u = 0; u < NCTL; ++u) {
        float x = cst[u];
        s_cost[u][tid] = fmaxf(x, 0.0f) + log1pf(expf(-fabsf(x))) + 1e-6f;
    }
    __syncthreads();               // cost visible

    // ---- value iteration: wave 0 only, DPP left/right, shfl up/down ----
    if (tid < 64) {
        const int cv  = tid & 15;
        const int rgv = tid >> 4;
        const int r0  = rgv * 4;

        float cs[4][NCTL];
        #pragma unroll
        for (int i = 0; i < 4; ++i)
            #pragma unroll
            for (int u = 0; u < NCTL; ++u)
                cs[i][u] = s_cost[u][(r0 + i) * GSZ + cv];

        const int grr = goal[2 * b], gcc = goal[2 * b + 1];
        float g[4];
        #pragma unroll
        for (int i = 0; i < 4; ++i)
            g[i] = (cv == gcc && (r0 + i) == grr) ? 0.0f : LBIG;

        for (int k = 0; k < KMAX; ++k) {
            const float gu = __shfl_up(g[3], 16);
            const float gd = __shfl_down(g[0], 16);
            float lf[4], rt[4];
            #pragma unroll
            for (int i = 0; i < 4; ++i) { lf[i] = dpp_up1(g[i]); rt[i] = dpp_dn1(g[i]); }
            const float up0 = (rgv > 0) ? gu : LBIG;
            const float dn3 = (rgv < 3) ? gd : LBIG;
            #pragma unroll
            for (int i = 0; i < 4; ++i) {
                lf[i] = (cv > 0)  ? lf[i] : LBIG;
                rt[i] = (cv < 15) ? rt[i] : LBIG;
            }
            const float up[4] = { up0, g[0], g[1], g[2] };
            const float dn[4] = { g[1], g[2], g[3], dn3 };
            float ng[4];
            bool ch = false;
            #pragma unroll
            for (int i = 0; i < 4; ++i) {
                float q = fminf(fminf(cs[i][0] + up[i], cs[i][1] + dn[i]),
                                fminf(cs[i][2] + lf[i], cs[i][3] + rt[i]));
                ng[i] = fminf(g[i], q);
                ch = ch || (ng[i] < g[i]);
            }
            #pragma unroll
            for (int i = 0; i < 4; ++i) g[i] = ng[i];
            if (__ballot(ch) == 0ULL) break;   // fixed point
        }

        #pragma unroll
        for (int i = 0; i < 4; ++i)
            s_gout[(r0 + i) * GSZ + cv] = g[i];
    }
    __syncthreads();

    // ---- Q gather + output softmax ----
    if (tid == 0) {
        const int lr = loc[2 * b], lc = loc[2 * b + 1];
        const int lp = lr * GSZ + lc;
        float Q0 = s_cost[0][lp] + s_gout[lp - GSZ];
        float Q1 = s_cost[1][lp] + s_gout[lp + GSZ];
        float Q2 = s_cost[2][lp] + s_gout[lp - 1];
        float Q3 = s_cost[3][lp] + s_gout[lp + 1];
        float l0 = -Q0, l1 = -Q1, l2 = -Q2, l3 = -Q3;
        float m  = fmaxf(fmaxf(l0, l1), fmaxf(l2, l3));
        float e0 = expf(l0 - m), e1 = expf(l1 - m), e2 = expf(l2 - m), e3 = expf(l3 - m);
        float inv = 1.0f / (e0 + e1 + e2 + e3);
        float* lo = out + (size_t)b * 4;
        float* po = out + (size_t)B * 4 + (size_t)b * 4;
        lo[0] = l0; lo[1] = l1; lo[2] = l2; lo[3] = l3;
        po[0] = e0 * inv; po[1] = e1 * inv; po[2] = e2 * inv; po[3] = e3 * inv;
    }
}

extern "C" void kernel_launch(void* const* d_in, const int* in_sizes, int n_in,
                              void* d_out, int out_size, void* d_ws, size_t ws_size,
                              hipStream_t stream) {
    const float* grid_cnt = (const float*)d_in[0];
    const int*   loc      = (const int*)  d_in[1];
    const int*   goal     = (const int*)  d_in[2];
    const float* theta    = (const float*)d_in[3];
    const float* w1       = (const float*)d_in[4];
    const float* b1       = (const float*)d_in[5];
    const float* w2       = (const float*)d_in[6];
    const float* b2       = (const float*)d_in[7];
    float*       outp     = (float*)d_out;
    unsigned*    pw       = (unsigned*)d_ws;     // needs 9216 B
    const int B = in_sizes[1] / 2;   // loc_batch is (B,2)

    hipLaunchKernelGGL(pack_weights, dim3(9), dim3(256), 0, stream, w1, w2, pw);
    hipLaunchKernelGGL(semirl_kernel, dim3(B), dim3(256), 0, stream,
                       grid_cnt, loc, goal, theta, b1, b2, pw, outp, B);
}

// Round 6
// 64.038 us; speedup vs baseline: 2.7039x; 1.4245x over previous
//
#include <hip/hip_runtime.h>
#include <math.h>

#define GSZ   16
#define NPIX  256
#define NCTL  4
#define LBIG  1.0e6f
#define KMAX  256
#define PW    18
#define PP18  324

typedef __fp16 f16x8 __attribute__((ext_vector_type(8)));
typedef float  f32x4 __attribute__((ext_vector_type(4)));
typedef __fp16 h2v   __attribute__((ext_vector_type(2)));
union UH2 { unsigned u; h2v h; };
union F8U { f16x8 h; uint4 u; unsigned w[4]; };
union UF  { unsigned u; float f; };

__device__ __forceinline__ unsigned pk2(float a, float b) {
    UH2 u; u.h = __builtin_amdgcn_cvt_pkrtz(a, b);
    return u.u;
}
// value from lane-1 within each 16-lane row: DPP row_shr:1
__device__ __forceinline__ float dpp_up1(float x) {
    UF s; s.f = x;
    UF r; r.u = __builtin_amdgcn_update_dpp(0, (int)s.u, 0x111, 0xF, 0xF, true);
    return r.f;
}
// value from lane+1 within each 16-lane row: DPP row_shl:1
__device__ __forceinline__ float dpp_dn1(float x) {
    UF s; s.f = x;
    UF r; r.u = __builtin_amdgcn_update_dpp(0, (int)s.u, 0x101, 0xF, 0xF, true);
    return r.f;
}

// ---- prep: pack weights into exact MFMA B-fragment order ----
// pw1f (4096 fp16): idx = ((ks*4+nt)*64+lane)*8+j ; k=ks*32+(lane>>4)*8+j ;
//   tap=k>>2, cls=k&3 ; val = tap<9 ? w1[oc=nt*16+(lane&15)][cls][tap] : 0
// pw2f (9216 fp16): idx = ((tap*2+ks)*64+lane)*8+j ; oc=ks*32+(lane>>4)*8+j ;
//   val = (u=lane&15)<4 ? w2[u][oc][tap] : 0
__global__ void pack_weights(const float* __restrict__ w1,
                             const float* __restrict__ w2,
                             __fp16* __restrict__ pw) {
    int i = blockIdx.x * 256 + threadIdx.x;
    if (i < 4096) {
        int j = i & 7, lane = (i >> 3) & 63, t = i >> 9;   // t = ks*4+nt
        int ks = t >> 2, nt = t & 3;
        int oc = nt * 16 + (lane & 15);
        int k  = ks * 32 + ((lane >> 4) & 3) * 8 + j;
        int tap = k >> 2, cls = k & 3;
        pw[i] = (tap < 9) ? (__fp16)w1[oc * 36 + cls * 9 + tap] : (__fp16)0.0f;
    } else if (i < 4096 + 9216) {
        int m = i - 4096;
        int j = m & 7, lane = (m >> 3) & 63, t = m >> 9;   // t = tap*2+ks
        int ks = t & 1, tap = t >> 1;
        int u  = lane & 15;
        int oc = ks * 32 + ((lane >> 4) & 3) * 8 + j;
        pw[i] = (u < 4) ? (__fp16)w2[u * 576 + oc * 9 + tap] : (__fp16)0.0f;
    }
}

__global__ __launch_bounds__(256, 3) void semirl_kernel(
    const float*  __restrict__ grid_cnt,  // (B,4,16,16)
    const int*    __restrict__ loc,       // (B,2)
    const int*    __restrict__ goal,      // (B,2)
    const float*  __restrict__ theta,     // (4,16,16)
    const float*  __restrict__ b1,        // (64)
    const float*  __restrict__ b2,        // (4)
    const __fp16* __restrict__ pw,        // packed weight fragments (d_ws)
    float*        __restrict__ out,       // logits (B,4) then probs (B,4)
    int B)
{
    const int b   = blockIdx.x;
    const int tid = threadIdx.x;
    const int lane = tid & 63;
    const int wv   = tid >> 6;          // wave id 0..3
    const int g    = (lane >> 4) & 3;   // k-group
    const int ln   = lane & 15;

    __shared__ uint2 s_sem[PP18];          // fp16x2 class pairs, zero ring
    __shared__ uint4 s_h4[PP18 * 8];       // fp16[ringpix][64oc], byte ^= (pix&7)<<4
    __shared__ float s_cost[NCTL][NPIX];
    __shared__ float s_gout[NPIX];
    char* s_hb = (char*)s_h4;

    // ---- phase 0: zero LDS, per-pixel class softmax ----
    for (int i = tid; i < PP18; i += 256) s_sem[i] = make_uint2(0u, 0u);
    for (int i = tid; i < PP18 * 8; i += 256) s_h4[i] = make_uint4(0u, 0u, 0u, 0u);

    unsigned semA, semB;
    {
        const float* gb = grid_cnt + (size_t)b * (4 * NPIX);
        float x0 = gb[0 * NPIX + tid] * theta[0 * NPIX + tid];
        float x1 = gb[1 * NPIX + tid] * theta[1 * NPIX + tid];
        float x2 = gb[2 * NPIX + tid] * theta[2 * NPIX + tid];
        float x3 = gb[3 * NPIX + tid] * theta[3 * NPIX + tid];
        float m  = fmaxf(fmaxf(x0, x1), fmaxf(x2, x3));
        float e0 = expf(x0 - m), e1 = expf(x1 - m), e2 = expf(x2 - m), e3 = expf(x3 - m);
        float inv = 1.0f / (e0 + e1 + e2 + e3);
        semA = pk2(e0 * inv, e1 * inv);
        semB = pk2(e2 * inv, e3 * inv);
    }
    __syncthreads();
    {
        const int pr = tid >> 4, pc = tid & 15;
        s_sem[(pr + 1) * PW + (pc + 1)] = make_uint2(semA, semB);
    }
    __syncthreads();

    // ---- conv1: M=256 N=64 K=36(pad64), 16x16x32 f16 MFMA ----
    F8U w1f[2][4];
    {
        const uint4* p1 = (const uint4*)pw;
        #pragma unroll
        for (int ks = 0; ks < 2; ++ks)
            #pragma unroll
            for (int nt = 0; nt < 4; ++nt)
                w1f[ks][nt].u = p1[(ks * 4 + nt) * 64 + lane];
    }
    const float bias1[4] = { b1[ln], b1[16 + ln], b1[32 + ln], b1[48 + ln] };
    // per-lane-group tap offsets: group g holds taps {2g, 2g+1} in k-step 0
    const int off0 = (g == 0) ? (-PW - 1) : (g == 1) ? (-PW + 1) : (g == 2) ? 0 : (PW - 1);
    const int off1 = (g == 0) ? (-PW)     : (g == 1) ? (-1)      : (g == 2) ? 1 : PW;

    #pragma unroll
    for (int i = 0; i < 4; ++i) {
        const int mt = wv * 4 + i;                 // M-tile = grid row
        const int pp = (mt + 1) * PW + (ln + 1);   // ring index of pixel (mt, ln)
        const uint2 A0 = s_sem[pp + off0];
        const uint2 A1 = s_sem[pp + off1];
        const uint2 A2 = s_sem[pp + (PW + 1)];     // tap8; dead slots have zero weights
        F8U a0, a1;
        a0.w[0] = A0.x; a0.w[1] = A0.y; a0.w[2] = A1.x; a0.w[3] = A1.y;
        a1.w[0] = A2.x; a1.w[1] = A2.y; a1.w[2] = 0u;  a1.w[3] = 0u;
        #pragma unroll
        for (int nt = 0; nt < 4; ++nt) {
            f32x4 acc = { bias1[nt], bias1[nt], bias1[nt], bias1[nt] };
            acc = __builtin_amdgcn_mfma_f32_16x16x32_f16(a0.h, w1f[0][nt].h, acc, 0, 0, 0);
            acc = __builtin_amdgcn_mfma_f32_16x16x32_f16(a1.h, w1f[1][nt].h, acc, 0, 0, 0);
            // C: col = oc = nt*16+ln (lane&15), row = pixel m = g*4+reg
            #pragma unroll
            for (int reg = 0; reg < 4; ++reg) {
                const int qq = (mt + 1) * PW + (g * 4 + reg + 1);   // ring idx of pixel
                int byte = qq * 128 + (nt * 16 + ln) * 2;
                byte ^= (qq & 7) << 4;
                *(__fp16*)(s_hb + byte) = (__fp16)fmaxf(acc[reg], 0.0f);
            }
        }
    }
    __syncthreads();

    // ---- conv2: 9 tap-GEMMs, M=256 N=16(4 real) K=64 ----
    F8U w2f[9][2];
    {
        const uint4* p2 = (const uint4*)(pw + 4096);
        #pragma unroll
        for (int tp = 0; tp < 9; ++tp)
            #pragma unroll
            for (int ks = 0; ks < 2; ++ks)
                w2f[tp][ks].u = p2[(tp * 2 + ks) * 64 + lane];
    }
    const float bias2 = (ln < 4) ? b2[ln] : 0.0f;
    const int OFF[9] = { -PW - 1, -PW, -PW + 1, -1, 0, 1, PW - 1, PW, PW + 1 };

    #pragma unroll
    for (int i = 0; i < 4; ++i) {
        const int mt = wv * 4 + i;
        const int pp = (mt + 1) * PW + (ln + 1);
        f32x4 cacc = { bias2, bias2, bias2, bias2 };
        #pragma unroll
        for (int tp = 0; tp < 9; ++tp) {
            const int ppn = pp + OFF[tp];
            const int sw  = (ppn & 7) << 4;
            #pragma unroll
            for (int ks = 0; ks < 2; ++ks) {
                F8U af;
                af.u = *(const uint4*)(s_hb + ((ppn * 128 + ks * 64 + g * 16) ^ sw));
                cacc = __builtin_amdgcn_mfma_f32_16x16x32_f16(af.h, w2f[tp][ks].h, cacc, 0, 0, 0);
            }
        }
        if (ln < 4) {
            #pragma unroll
            for (int reg = 0; reg < 4; ++reg) {
                const int q = mt * 16 + g * 4 + reg;
                float x = cacc[reg];
                s_cost[ln][q] = fmaxf(x, 0.0f) + log1pf(expf(-fabsf(x))) + 1e-6f;
            }
        }
    }
    __syncthreads();

    // ---- value iteration: wave 0 only, DPP left/right, shfl up/down ----
    if (tid < 64) {
        const int cv  = tid & 15;
        const int rgv = tid >> 4;
        const int r0  = rgv * 4;

        float cs[4][NCTL];
        #pragma unroll
        for (int i = 0; i < 4; ++i)
            #pragma unroll
            for (int u = 0; u < NCTL; ++u)
                cs[i][u] = s_cost[u][(r0 + i) * GSZ + cv];

        const int grr = goal[2 * b], gcc = goal[2 * b + 1];
        float gg[4];
        #pragma unroll
        for (int i = 0; i < 4; ++i)
            gg[i] = (cv == gcc && (r0 + i) == grr) ? 0.0f : LBIG;

        for (int k = 0; k < KMAX; ++k) {
            const float gu = __shfl_up(gg[3], 16);
            const float gd = __shfl_down(gg[0], 16);
            float lf[4], rt[4];
            #pragma unroll
            for (int i = 0; i < 4; ++i) { lf[i] = dpp_up1(gg[i]); rt[i] = dpp_dn1(gg[i]); }
            const float up0 = (rgv > 0) ? gu : LBIG;
            const float dn3 = (rgv < 3) ? gd : LBIG;
            #pragma unroll
            for (int i = 0; i < 4; ++i) {
                lf[i] = (cv > 0)  ? lf[i] : LBIG;
                rt[i] = (cv < 15) ? rt[i] : LBIG;
            }
            const float up[4] = { up0, gg[0], gg[1], gg[2] };
            const float dn[4] = { gg[1], gg[2], gg[3], dn3 };
            float ng[4];
            bool ch = false;
            #pragma unroll
            for (int i = 0; i < 4; ++i) {
                float q = fminf(fminf(cs[i][0] + up[i], cs[i][1] + dn[i]),
                                fminf(cs[i][2] + lf[i], cs[i][3] + rt[i]));
                ng[i] = fminf(gg[i], q);
                ch = ch || (ng[i] < gg[i]);
            }
            #pragma unroll
            for (int i = 0; i < 4; ++i) gg[i] = ng[i];
            if (__ballot(ch) == 0ULL) break;   // fixed point
        }

        #pragma unroll
        for (int i = 0; i < 4; ++i)
            s_gout[(r0 + i) * GSZ + cv] = gg[i];
    }
    __syncthreads();

    // ---- Q gather + output softmax ----
    if (tid == 0) {
        const int lr = loc[2 * b], lc = loc[2 * b + 1];
        const int lp = lr * GSZ + lc;
        float Q0 = s_cost[0][lp] + s_gout[lp - GSZ];
        float Q1 = s_cost[1][lp] + s_gout[lp + GSZ];
        float Q2 = s_cost[2][lp] + s_gout[lp - 1];
        float Q3 = s_cost[3][lp] + s_gout[lp + 1];
        float l0 = -Q0, l1 = -Q1, l2 = -Q2, l3 = -Q3;
        float m  = fmaxf(fmaxf(l0, l1), fmaxf(l2, l3));
        float e0 = expf(l0 - m), e1 = expf(l1 - m), e2 = expf(l2 - m), e3 = expf(l3 - m);
        float inv = 1.0f / (e0 + e1 + e2 + e3);
        float* lo = out + (size_t)b * 4;
        float* po = out + (size_t)B * 4 + (size_t)b * 4;
        lo[0] = l0; lo[1] = l1; lo[2] = l2; lo[3] = l3;
        po[0] = e0 * inv; po[1] = e1 * inv; po[2] = e2 * inv; po[3] = e3 * inv;
    }
}

extern "C" void kernel_launch(void* const* d_in, const int* in_sizes, int n_in,
                              void* d_out, int out_size, void* d_ws, size_t ws_size,
                              hipStream_t stream) {
    const float* grid_cnt = (const float*)d_in[0];
    const int*   loc      = (const int*)  d_in[1];
    const int*   goal     = (const int*)  d_in[2];
    const float* theta    = (const float*)d_in[3];
    const float* w1       = (const float*)d_in[4];
    const float* b1       = (const float*)d_in[5];
    const float* w2       = (const float*)d_in[6];
    const float* b2       = (const float*)d_in[7];
    float*       outp     = (float*)d_out;
    __fp16*      pw       = (__fp16*)d_ws;     // needs 26624 B
    const int B = in_sizes[1] / 2;   // loc_batch is (B,2)

    hipLaunchKernelGGL(pack_weights, dim3(52), dim3(256), 0, stream, w1, w2, pw);
    hipLaunchKernelGGL(semirl_kernel, dim3(B), dim3(256), 0, stream,
                       grid_cnt, loc, goal, theta, b1, b2, pw, outp, B);
}

// Round 7
// 58.134 us; speedup vs baseline: 2.9785x; 1.1016x over previous
//
#include <hip/hip_runtime.h>
#include <math.h>

#define GSZ   16
#define NPIX  256
#define NCTL  4
#define LBIG  1.0e6f
#define PW    18
#define PP18  324

typedef __fp16 f16x8 __attribute__((ext_vector_type(8)));
typedef float  f32x4 __attribute__((ext_vector_type(4)));
typedef __fp16 h2v   __attribute__((ext_vector_type(2)));
union UH2 { unsigned u; h2v h; };
union F8U { f16x8 h; uint4 u; unsigned w[4]; };
union UF  { unsigned u; float f; };

__device__ __forceinline__ unsigned pk2(float a, float b) {
    UH2 u; u.h = __builtin_amdgcn_cvt_pkrtz(a, b);
    return u.u;
}
// value from lane-1 within each 16-lane row: DPP row_shr:1
__device__ __forceinline__ float dpp_up1(float x) {
    UF s; s.f = x;
    UF r; r.u = __builtin_amdgcn_update_dpp(0, (int)s.u, 0x111, 0xF, 0xF, true);
    return r.f;
}
// value from lane+1 within each 16-lane row: DPP row_shl:1
__device__ __forceinline__ float dpp_dn1(float x) {
    UF s; s.f = x;
    UF r; r.u = __builtin_amdgcn_update_dpp(0, (int)s.u, 0x101, 0xF, 0xF, true);
    return r.f;
}

// ---- prep: pack weights into MFMA fragment order (same data serves either
// operand role; fragment layouts are symmetric in lane&15 / k) ----
// pw1f (4096 fp16): idx = ((ks*4+nt)*64+lane)*8+j ; k=ks*32+(lane>>4)*8+j ;
//   tap=k>>2, cls=k&3 ; val = tap<9 ? w1[oc=nt*16+(lane&15)][cls][tap] : 0
// pw2f (9216 fp16): idx = ((tap*2+ks)*64+lane)*8+j ; oc=ks*32+(lane>>4)*8+j ;
//   val = (u=lane&15)<4 ? w2[u][oc][tap] : 0
__global__ void pack_weights(const float* __restrict__ w1,
                             const float* __restrict__ w2,
                             __fp16* __restrict__ pw) {
    int i = blockIdx.x * 256 + threadIdx.x;
    if (i < 4096) {
        int j = i & 7, lane = (i >> 3) & 63, t = i >> 9;   // t = ks*4+nt
        int ks = t >> 2, nt = t & 3;
        int oc = nt * 16 + (lane & 15);
        int k  = ks * 32 + ((lane >> 4) & 3) * 8 + j;
        int tap = k >> 2, cls = k & 3;
        pw[i] = (tap < 9) ? (__fp16)w1[oc * 36 + cls * 9 + tap] : (__fp16)0.0f;
    } else if (i < 4096 + 9216) {
        int m = i - 4096;
        int j = m & 7, lane = (m >> 3) & 63, t = m >> 9;   // t = tap*2+ks
        int ks = t & 1, tap = t >> 1;
        int u  = lane & 15;
        int oc = ks * 32 + ((lane >> 4) & 3) * 8 + j;
        pw[i] = (u < 4) ? (__fp16)w2[u * 576 + oc * 9 + tap] : (__fp16)0.0f;
    }
}

// ring index for border pixel t in [0,68)
__device__ __forceinline__ int ring_idx(int t) {
    return (t < 18) ? t
         : (t < 36) ? (306 + (t - 18))
         : (t < 52) ? ((t - 35) * PW)
                    : ((t - 51) * PW + 17);
}

__global__ __launch_bounds__(256, 3) void semirl_kernel(
    const float*  __restrict__ grid_cnt,  // (B,4,16,16)
    const int*    __restrict__ loc,       // (B,2)
    const int*    __restrict__ goal,      // (B,2)
    const float*  __restrict__ theta,     // (4,16,16)
    const float*  __restrict__ b1,        // (64)
    const float*  __restrict__ b2,        // (4)
    const __fp16* __restrict__ pw,        // packed weight fragments (d_ws)
    float*        __restrict__ out,       // logits (B,4) then probs (B,4)
    int B)
{
    const int b    = blockIdx.x;
    const int tid  = threadIdx.x;
    const int lane = tid & 63;
    const int wv   = tid >> 6;          // wave id 0..3
    const int g    = (lane >> 4) & 3;   // k-group / row-group
    const int ln   = lane & 15;

    __shared__ uint2 s_sem[PP18];          // fp16x2 class pairs, zero ring
    __shared__ uint4 s_h4[PP18 * 8];       // fp16[ringpix][64oc], byte ^= (pix&7)<<4
    __shared__ float s_cost[NCTL][NPIX];
    __shared__ float s_gout[NPIX];
    char* s_hb = (char*)s_h4;

    // ---- prefetch ALL globals first (latency hides under phase 0) ----
    F8U w1f[2][4];
    {
        const uint4* p1 = (const uint4*)pw;
        #pragma unroll
        for (int ks = 0; ks < 2; ++ks)
            #pragma unroll
            for (int nt = 0; nt < 4; ++nt)
                w1f[ks][nt].u = p1[(ks * 4 + nt) * 64 + lane];
    }
    F8U w2f[9][2];
    {
        const uint4* p2 = (const uint4*)(pw + 4096);
        #pragma unroll
        for (int tp = 0; tp < 9; ++tp)
            #pragma unroll
            for (int ks = 0; ks < 2; ++ks)
                w2f[tp][ks].u = p2[(tp * 2 + ks) * 64 + lane];
    }
    float4 bias1v[4];
    #pragma unroll
    for (int nt = 0; nt < 4; ++nt)
        bias1v[nt] = *(const float4*)&b1[nt * 16 + g * 4];
    const float4 b2v = *(const float4*)b2;
    const int grr = goal[2 * b], gcc = goal[2 * b + 1];
    const int lr  = loc[2 * b],  lc  = loc[2 * b + 1];

    const float* gb = grid_cnt + (size_t)b * (4 * NPIX);
    const float gi0 = gb[0 * NPIX + tid], th0 = theta[0 * NPIX + tid];
    const float gi1 = gb[1 * NPIX + tid], th1 = theta[1 * NPIX + tid];
    const float gi2 = gb[2 * NPIX + tid], th2 = theta[2 * NPIX + tid];
    const float gi3 = gb[3 * NPIX + tid], th3 = theta[3 * NPIX + tid];

    // ---- phase 0: ring-only zero fill + per-pixel class softmax ----
    if (tid < 68) s_sem[ring_idx(tid)] = make_uint2(0u, 0u);
    for (int i2 = tid; i2 < 544; i2 += 256) {
        int qq = ring_idx(i2 >> 3);
        s_h4[qq * 8 + (i2 & 7)] = make_uint4(0u, 0u, 0u, 0u);
    }
    {
        float x0 = gi0 * th0, x1 = gi1 * th1, x2 = gi2 * th2, x3 = gi3 * th3;
        float m  = fmaxf(fmaxf(x0, x1), fmaxf(x2, x3));
        float e0 = expf(x0 - m), e1 = expf(x1 - m), e2 = expf(x2 - m), e3 = expf(x3 - m);
        float inv = 1.0f / (e0 + e1 + e2 + e3);
        const int pr = tid >> 4, pc = tid & 15;
        s_sem[(pr + 1) * PW + (pc + 1)] =
            make_uint2(pk2(e0 * inv, e1 * inv), pk2(e2 * inv, e3 * inv));
    }
    __syncthreads();               // sem + rings ready

    // ---- conv1 (swapped operands: D' = W^T x Act^T) ----
    // per-lane-group tap offsets: group g holds taps {2g, 2g+1} in k-step 0
    const int off0 = (g == 0) ? (-PW - 1) : (g == 1) ? (-PW + 1) : (g == 2) ? 0 : (PW - 1);
    const int off1 = (g == 0) ? (-PW)     : (g == 1) ? (-1)      : (g == 2) ? 1 : PW;

    #pragma unroll
    for (int i = 0; i < 4; ++i) {
        const int mt = wv * 4 + i;                 // grid row
        const int pp = (mt + 1) * PW + (ln + 1);   // ring index of pixel (mt, ln)
        const uint2 A0 = s_sem[pp + off0];
        const uint2 A1 = s_sem[pp + off1];
        const uint2 A2 = s_sem[pp + (PW + 1)];     // tap8; dead slots have zero weights
        F8U a0, a1;
        a0.w[0] = A0.x; a0.w[1] = A0.y; a0.w[2] = A1.x; a0.w[3] = A1.y;
        a1.w[0] = A2.x; a1.w[1] = A2.y; a1.w[2] = 0u;  a1.w[3] = 0u;
        #pragma unroll
        for (int nt = 0; nt < 4; ++nt) {
            f32x4 acc = { bias1v[nt].x, bias1v[nt].y, bias1v[nt].z, bias1v[nt].w };
            acc = __builtin_amdgcn_mfma_f32_16x16x32_f16(w1f[0][nt].h, a0.h, acc, 0, 0, 0);
            acc = __builtin_amdgcn_mfma_f32_16x16x32_f16(w1f[1][nt].h, a1.h, acc, 0, 0, 0);
            // D': col = pixel ln, row = oc = nt*16 + g*4 + reg -> 8B contiguous
            uint2 hv;
            hv.x = pk2(fmaxf(acc[0], 0.0f), fmaxf(acc[1], 0.0f));
            hv.y = pk2(fmaxf(acc[2], 0.0f), fmaxf(acc[3], 0.0f));
            int byte = pp * 128 + (nt * 16 + g * 4) * 2;
            byte ^= (pp & 7) << 4;
            *(uint2*)(s_hb + byte) = hv;
        }
    }
    __syncthreads();

    // ---- conv2 (swapped): 9 tap-GEMMs, rows = u (g==0 lanes real) ----
    const int OFF[9] = { -PW - 1, -PW, -PW + 1, -1, 0, 1, PW - 1, PW, PW + 1 };
    #pragma unroll
    for (int i = 0; i < 4; ++i) {
        const int mt = wv * 4 + i;
        const int pp = (mt + 1) * PW + (ln + 1);
        f32x4 cacc;
        cacc[0] = (g == 0) ? b2v.x : 0.0f;
        cacc[1] = (g == 0) ? b2v.y : 0.0f;
        cacc[2] = (g == 0) ? b2v.z : 0.0f;
        cacc[3] = (g == 0) ? b2v.w : 0.0f;
        #pragma unroll
        for (int tp = 0; tp < 9; ++tp) {
            const int ppn = pp + OFF[tp];
            const int sw  = (ppn & 7) << 4;
            #pragma unroll
            for (int ks = 0; ks < 2; ++ks) {
                F8U af;
                af.u = *(const uint4*)(s_hb + ((ppn * 128 + ks * 64 + g * 16) ^ sw));
                cacc = __builtin_amdgcn_mfma_f32_16x16x32_f16(w2f[tp][ks].h, af.h, cacc, 0, 0, 0);
            }
        }
        if (g == 0) {
            #pragma unroll
            for (int reg = 0; reg < 4; ++reg) {
                float x = cacc[reg];
                s_cost[reg][mt * 16 + ln] =
                    fmaxf(x, 0.0f) + log1pf(expf(-fabsf(x))) + 1e-6f;
            }
        }
    }
    __syncthreads();

    // ---- value iteration: wave 0; 2 inner relaxations per boundary exchange.
    // Monotone min-relaxation: stale boundaries stay correct; no-change over
    // both inners => inner-1 was a fresh full Jacobi no-op => exact fixed point.
    if (tid < 64) {
        const int cv  = tid & 15;
        const int rgv = tid >> 4;
        const int r0  = rgv * 4;

        float cs[4][NCTL];
        #pragma unroll
        for (int i = 0; i < 4; ++i)
            #pragma unroll
            for (int u = 0; u < NCTL; ++u)
                cs[i][u] = s_cost[u][(r0 + i) * GSZ + cv];

        float gg[4];
        #pragma unroll
        for (int i = 0; i < 4; ++i)
            gg[i] = (cv == gcc && (r0 + i) == grr) ? 0.0f : LBIG;

        for (int k = 0; k < 128; ++k) {
            const float gu = __shfl_up(gg[3], 16);
            const float gd = __shfl_down(gg[0], 16);
            const float up0 = (rgv > 0) ? gu : LBIG;
            const float dn3 = (rgv < 3) ? gd : LBIG;
            bool ch = false;
            #pragma unroll
            for (int s = 0; s < 2; ++s) {
                float lf[4], rt[4];
                #pragma unroll
                for (int i = 0; i < 4; ++i) { lf[i] = dpp_up1(gg[i]); rt[i] = dpp_dn1(gg[i]); }
                #pragma unroll
                for (int i = 0; i < 4; ++i) {
                    lf[i] = (cv > 0)  ? lf[i] : LBIG;
                    rt[i] = (cv < 15) ? rt[i] : LBIG;
                }
                const float up[4] = { up0, gg[0], gg[1], gg[2] };
                const float dn[4] = { gg[1], gg[2], gg[3], dn3 };
                #pragma unroll
                for (int i = 0; i < 4; ++i) {
                    float q = fminf(fminf(cs[i][0] + up[i], cs[i][1] + dn[i]),
                                    fminf(cs[i][2] + lf[i], cs[i][3] + rt[i]));
                    float ng = fminf(gg[i], q);
                    ch = ch || (ng < gg[i]);
                    gg[i] = ng;
                }
            }
            if (__ballot(ch) == 0ULL) break;   // fixed point
        }

        #pragma unroll
        for (int i = 0; i < 4; ++i)
            s_gout[(r0 + i) * GSZ + cv] = gg[i];
    }
    __syncthreads();

    // ---- Q gather + output softmax ----
    if (tid == 0) {
        const int lp = lr * GSZ + lc;
        float Q0 = s_cost[0][lp] + s_gout[lp - GSZ];
        float Q1 = s_cost[1][lp] + s_gout[lp + GSZ];
        float Q2 = s_cost[2][lp] + s_gout[lp - 1];
        float Q3 = s_cost[3][lp] + s_gout[lp + 1];
        float l0 = -Q0, l1 = -Q1, l2 = -Q2, l3 = -Q3;
        float m  = fmaxf(fmaxf(l0, l1), fmaxf(l2, l3));
        float e0 = expf(l0 - m), e1 = expf(l1 - m), e2 = expf(l2 - m), e3 = expf(l3 - m);
        float inv = 1.0f / (e0 + e1 + e2 + e3);
        float* lo = out + (size_t)b * 4;
        float* po = out + (size_t)B * 4 + (size_t)b * 4;
        lo[0] = l0; lo[1] = l1; lo[2] = l2; lo[3] = l3;
        po[0] = e0 * inv; po[1] = e1 * inv; po[2] = e2 * inv; po[3] = e3 * inv;
    }
}

extern "C" void kernel_launch(void* const* d_in, const int* in_sizes, int n_in,
                              void* d_out, int out_size, void* d_ws, size_t ws_size,
                              hipStream_t stream) {
    const float* grid_cnt = (const float*)d_in[0];
    const int*   loc      = (const int*)  d_in[1];
    const int*   goal     = (const int*)  d_in[2];
    const float* theta    = (const float*)d_in[3];
    const float* w1       = (const float*)d_in[4];
    const float* b1       = (const float*)d_in[5];
    const float* w2       = (const float*)d_in[6];
    const float* b2       = (const float*)d_in[7];
    float*       outp     = (float*)d_out;
    __fp16*      pw       = (__fp16*)d_ws;     // needs 26624 B
    const int B = in_sizes[1] / 2;   // loc_batch is (B,2)

    hipLaunchKernelGGL(pack_weights, dim3(52), dim3(256), 0, stream, w1, w2, pw);
    hipLaunchKernelGGL(semirl_kernel, dim3(B), dim3(256), 0, stream,
                       grid_cnt, loc, goal, theta, b1, b2, pw, outp, B);
}